// Round 1
// baseline (50.766 us; speedup 1.0000x reference)
//
#include <hip/hip_runtime.h>

// FFM layer forward.
// inputs: idx [B,16] int32, w0 [1] f32, w [1048576,1] f32, v [1048576,16,8] f32
// out:    [B,1] f32
//
// One wave (64 lanes) per sample. Half-wave h (lanes h*32..h*32+31) accumulates
// fields i = 2t+h, t=0..7: each lane reads float4 at row offset (lane&31)*4,
// so 32 lanes fetch one full 512B row per iteration (fully coalesced, 16B/lane).
// acc[lane&31] after half-combine holds lv at flats 4c..4c+3 (c = lane&31):
//   flat = 8*(c>>1) + 4*(c&1) + e  ->  j = c>>1, k = 4*(c&1)+e.
// s[k] reduction = butterfly over masks {2,4,8,16} (lanes sharing bit0 share k-quad).
// sq / wsum = butterfly over masks {1,2,4,8,16} within a 32-lane half.

constexpr int F   = 16;
constexpr int K   = 8;
constexpr int PFV = 65536;
constexpr int ROW = F * K;  // 128 floats = 512 B

__global__ __launch_bounds__(256) void ffm_fwd(
    const int* __restrict__ idx, const float* __restrict__ w0,
    const float* __restrict__ w, const float* __restrict__ v,
    float* __restrict__ out, int nB)
{
  const int gtid = blockIdx.x * 256 + threadIdx.x;
  const int b    = gtid >> 6;
  const int lane = threadIdx.x & 63;
  if (b >= nB) return;

  // Each of lanes 0..15 owns one field's (offset) index + linear weight.
  int   my   = 0;
  float wsum = 0.f;
  if (lane < F) {
    my   = idx[b * F + lane] + lane * PFV;
    wsum = w[my];
  }

  const int half = lane >> 5;   // which field-parity this half-wave handles
  const int c    = lane & 31;

  float4 acc = make_float4(0.f, 0.f, 0.f, 0.f);
#pragma unroll
  for (int t = 0; t < F / 2; ++t) {
    const int r = __shfl(my, 2 * t + half, 64);     // field i = 2t+half
    const float4* row = (const float4*)(v + (size_t)r * ROW);
    const float4 x = row[c];
    acc.x += x.x; acc.y += x.y; acc.z += x.z; acc.w += x.w;
  }

  // Combine the two half-wave partial sums: now acc = lv[4c .. 4c+3] (dup'd across halves).
  acc.x += __shfl_xor(acc.x, 32, 64);
  acc.y += __shfl_xor(acc.y, 32, 64);
  acc.z += __shfl_xor(acc.z, 32, 64);
  acc.w += __shfl_xor(acc.w, 32, 64);

  // sum of squares of lv (all 128 elements; each 32-lane half covers all flats)
  float q = acc.x * acc.x + acc.y * acc.y + acc.z * acc.z + acc.w * acc.w;

  // s[k] = sum over j: butterfly over lanes sharing bit0 within the half
  float4 s = acc;
#pragma unroll
  for (int m = 2; m <= 16; m <<= 1) {
    s.x += __shfl_xor(s.x, m, 64);
    s.y += __shfl_xor(s.y, m, 64);
    s.z += __shfl_xor(s.z, m, 64);
    s.w += __shfl_xor(s.w, m, 64);
  }
  float sp = s.x * s.x + s.y * s.y + s.z * s.z + s.w * s.w;
  sp += __shfl_xor(sp, 1, 64);   // add the other k-parity -> sum_k s_k^2

  // full reductions of q (within half) and wsum (lanes 0..15 live)
#pragma unroll
  for (int m = 1; m <= 16; m <<= 1) {
    q    += __shfl_xor(q, m, 64);
    wsum += __shfl_xor(wsum, m, 64);
  }

  if (lane == 0)
    out[b] = w0[0] + wsum + 0.5f * (sp - q);
}

extern "C" void kernel_launch(void* const* d_in, const int* in_sizes, int n_in,
                              void* d_out, int out_size, void* d_ws, size_t ws_size,
                              hipStream_t stream) {
  const int*   idx = (const int*)d_in[0];
  const float* w0  = (const float*)d_in[1];
  const float* w   = (const float*)d_in[2];
  const float* v   = (const float*)d_in[3];
  float*       out = (float*)d_out;

  const int nB = in_sizes[0] / F;          // 32768
  const int blocks = (nB + 3) / 4;         // 4 waves (samples) per 256-thread block
  ffm_fwd<<<blocks, 256, 0, stream>>>(idx, w0, w, v, out, nB);
}